// Round 9
// baseline (1221.583 us; speedup 1.0000x reference)
//
#include <hip/hip_runtime.h>
#include <hip/hip_bf16.h>
#include <math.h>

#define MDIM 2048
#define KDIM 1024
#define BIGF 1e9f
#define NSTRIP 32   // strips per matrix, 64 rows each (1 row per lane)
// KPH=32 steps/phase. Skew D=4 phases (128 steps). Strip s: phases [4s, 4s+65].

typedef unsigned short ushort;
typedef unsigned int uint;
typedef __attribute__((ext_vector_type(8))) short short8v;
typedef __attribute__((ext_vector_type(8))) ushort ushort8v;
typedef __attribute__((ext_vector_type(4))) float f32x4;
typedef __attribute__((ext_vector_type(4), aligned(4))) float f4u;

// ---------------- row normalization: one wave per row, emits bf16 ----------
__device__ __forceinline__ ushort f2bf(float f) {
  uint b = __builtin_bit_cast(uint, f);
  b += 0x7FFFu + ((b >> 16) & 1u);
  return (ushort)(b >> 16);
}

__global__ __launch_bounds__(256) void normalize_rows(
    const float* __restrict__ x, const float* __restrict__ y,
    ushort* __restrict__ xb, ushort* __restrict__ yb) {
  int wave = (blockIdx.x * blockDim.x + threadIdx.x) >> 6;
  int lane = threadIdx.x & 63;
  const float* src;
  ushort* dst;
  int row;
  if (wave < MDIM) { src = x; dst = xb; row = wave; }
  else             { src = y; dst = yb; row = wave - MDIM; }
  const float* r = src + (size_t)row * KDIM;
  ushort* w = dst + (size_t)row * KDIM;
  float ss = 0.f;
  for (int c = lane * 4; c < KDIM; c += 64 * 4) {
    float4 v = *(const float4*)&r[c];
    ss += v.x * v.x + v.y * v.y + v.z * v.z + v.w * v.w;
  }
  #pragma unroll
  for (int off = 32; off; off >>= 1) ss += __shfl_xor(ss, off, 64);
  float inv = 1.f / fmaxf(sqrtf(ss), 1e-12f);
  for (int c = lane * 4; c < KDIM; c += 64 * 4) {
    float4 v = *(const float4*)&r[c];
    uint2 o;
    o.x = (uint)f2bf(v.x * inv) | ((uint)f2bf(v.y * inv) << 16);
    o.y = (uint)f2bf(v.z * inv) | ((uint)f2bf(v.w * inv) << 16);
    *(uint2*)&w[c] = o;
  }
}

// ------------- cost GEMM (bf16 MFMA): C' = (1 - A.B^T) * kexp -------------
__global__ __launch_bounds__(256) void gemm_cost_mfma(
    const ushort* __restrict__ xb, const ushort* __restrict__ yb,
    float* __restrict__ cost_base, const float* __restrict__ gamma_p) {
  int z = blockIdx.z;
  const ushort* A = (z == 2) ? yb : xb;
  const ushort* B = (z == 0) ? yb : ((z == 1) ? xb : yb);
  float* C = cost_base + (size_t)z * MDIM * MDIM;
  float g = fmaxf(fabsf(gamma_p[0]), 1e-4f);
  float kexp = 1.44269504089f / g;

  __shared__ ushort As[128 * 64];
  __shared__ ushort Bs[128 * 64];

  int tid = threadIdx.x;
  int w = tid >> 6, l = tid & 63;
  int wr = w >> 1, wc = w & 1;
  int abase = blockIdx.y * 128;
  int bbase = blockIdx.x * 128;

  f32x4 acc[4][4] = {};

  for (int k0 = 0; k0 < KDIM; k0 += 64) {
    ushort8v va[4], vb[4];
    #pragma unroll
    for (int q = 0; q < 4; ++q) {
      int slot = q * 256 + tid;
      int row = slot >> 3, sc = slot & 7;
      va[q] = *(const ushort8v*)&A[(size_t)(abase + row) * KDIM + k0 + sc * 8];
      vb[q] = *(const ushort8v*)&B[(size_t)(bbase + row) * KDIM + k0 + sc * 8];
    }
    __syncthreads();
    #pragma unroll
    for (int q = 0; q < 4; ++q) {
      int slot = q * 256 + tid;
      int row = slot >> 3, sc = slot & 7;
      int off = row * 64 + ((sc ^ (row & 7)) << 3);
      *(ushort8v*)&As[off] = va[q];
      *(ushort8v*)&Bs[off] = vb[q];
    }
    __syncthreads();
    #pragma unroll
    for (int kk = 0; kk < 2; ++kk) {
      short8v af[4], bf[4];
      #pragma unroll
      for (int m = 0; m < 4; ++m) {
        int row = wr * 64 + m * 16 + (l & 15);
        int kg = kk * 4 + (l >> 4);
        af[m] = *(const short8v*)&As[row * 64 + ((kg ^ (row & 7)) << 3)];
      }
      #pragma unroll
      for (int n = 0; n < 4; ++n) {
        int row = wc * 64 + n * 16 + (l & 15);
        int kg = kk * 4 + (l >> 4);
        bf[n] = *(const short8v*)&Bs[row * 64 + ((kg ^ (row & 7)) << 3)];
      }
      #pragma unroll
      for (int m = 0; m < 4; ++m)
        #pragma unroll
        for (int n = 0; n < 4; ++n)
          acc[m][n] = __builtin_amdgcn_mfma_f32_16x16x32_bf16(
              af[m], bf[n], acc[m][n], 0, 0, 0);
    }
  }
  #pragma unroll
  for (int m = 0; m < 4; ++m) {
    int row0 = abase + wr * 64 + m * 16 + (l >> 4) * 4;
    #pragma unroll
    for (int n = 0; n < 4; ++n) {
      int col = bbase + wc * 64 + n * 16 + (l & 15);
      f32x4 v = acc[m][n];
      #pragma unroll
      for (int r = 0; r < 4; ++r)
        C[(size_t)(row0 + r) * MDIM + col] = (1.0f - v[r]) * kexp;
    }
  }
}

// ---------------- soft-DTW: SSA-register wavefront, KPH=32 ----------------
__device__ __forceinline__ float fexp2(float x) { return __builtin_amdgcn_exp2f(x); }
__device__ __forceinline__ float flog2(float x) { return __builtin_amdgcn_logf(x); }

__device__ __forceinline__ float shr1(float v) {  // lane i <- lane i-1
  int r = __builtin_amdgcn_update_dpp(__builtin_bit_cast(int, v),
                                      __builtin_bit_cast(int, v),
                                      0x138 /*wave_shr:1*/, 0xF, 0xF, false);
  return __builtin_bit_cast(float, r);
}

__device__ __forceinline__ float aload(const float* p) {
  return __hip_atomic_load(p, __ATOMIC_RELAXED, __HIP_MEMORY_SCOPE_AGENT);
}

// staged cost window: 8 named f4u fields, always passed/returned BY VALUE
// (pure SSA -> guaranteed register placement; arrays/references spilled in
// r5-r8: VGPR=48..108 < window size proved scratch residency)
struct W8 { f4u v0, v1, v2, v3, v4, v5, v6, v7; };

__device__ __forceinline__ W8 load_w(const float* __restrict__ crow, int base) {
  W8 w;
  w.v0 = *(const f4u*)&crow[base +  0];
  w.v1 = *(const f4u*)&crow[base +  4];
  w.v2 = *(const f4u*)&crow[base +  8];
  w.v3 = *(const f4u*)&crow[base + 12];
  w.v4 = *(const f4u*)&crow[base + 16];
  w.v5 = *(const f4u*)&crow[base + 20];
  w.v6 = *(const f4u*)&crow[base + 24];
  w.v7 = *(const f4u*)&crow[base + 28];
  return w;
}

__device__ __forceinline__ W8 load_w_edge(const float* __restrict__ crow,
                                          int base) {
  W8 w;
  f4u t[8];
  #pragma unroll
  for (int k = 0; k < 8; ++k)
    #pragma unroll
    for (int j = 0; j < 4; ++j) {
      int col = min(max(base + 4 * k + j, 0), MDIM - 1);
      t[k][j] = crow[col];
    }
  w.v0 = t[0]; w.v1 = t[1]; w.v2 = t[2]; w.v3 = t[3];
  w.v4 = t[4]; w.v5 = t[5]; w.v6 = t[6]; w.v7 = t[7];
  return w;
}

// one 32-step phase body; lane l owns row (64s + l); col at step u: cb+u-l.
template <bool FIRST, bool EDGE>
__device__ __forceinline__ void phase32(
    float& o, float& d, float bq, W8 w, int cb, int lane,
    float* __restrict__ bw) {
  const bool l0 = (lane == 0);
  const bool l63 = (lane == 63);
  float h0, h1, h2, h3;
  #pragma unroll
  for (int u = 0; u < 32; ++u) {
    f4u q = (u < 4) ? w.v0 : (u < 8) ? w.v1 : (u < 12) ? w.v2
          : (u < 16) ? w.v3 : (u < 20) ? w.v4 : (u < 24) ? w.v5
          : (u < 28) ? w.v6 : w.v7;
    float cv = q[u & 3];
    float t = shr1(o);
    float av;
    if (FIRST) {
      av = l0 ? BIGF : t;
    } else {
      float rv = __builtin_bit_cast(
          float, __builtin_amdgcn_readlane(__builtin_bit_cast(int, bq), u));
      av = l0 ? rv : t;
    }
    float mn, md, mx;
    asm("v_min3_f32 %0, %1, %2, %3" : "=v"(mn) : "v"(d), "v"(av), "v"(o));
    asm("v_med3_f32 %0, %1, %2, %3" : "=v"(md) : "v"(d), "v"(av), "v"(o));
    asm("v_max3_f32 %0, %1, %2, %3" : "=v"(mx) : "v"(d), "v"(av), "v"(o));
    float e = 1.0f + fexp2(mn - md) + fexp2(mn - mx);
    float n = cv + (mn - flog2(e));
    if (EDGE) {
      int c = cb + u - lane;
      bool valid = ((unsigned)c < (unsigned)MDIM);
      n = valid ? n : BIGF;
      if (l63 && valid) bw[c] = n;
    } else {
      if ((u & 3) == 0) h0 = n;
      else if ((u & 3) == 1) h1 = n;
      else if ((u & 3) == 2) h2 = n;
      else {
        h3 = n;
        if (l63) *(f4u*)&bw[cb + u - 66] = (f4u){h0, h1, h2, h3};
      }
    }
    d = av;
    o = n;
  }
}

// one full phase: acquire -> stage next window (SSA) -> body(cur) -> release.
template <bool FIRST>
__device__ __forceinline__ W8 do_phase(
    int dq, int s, int lane, W8 cur, float& o, float& d, float& bqN,
    const float* __restrict__ crow, const float* __restrict__ bp,
    float* __restrict__ bw, int* myf, int* predf, int& pcache) {
  const int p = 4 * s + dq;
  const int cb = dq << 5;
  if (!FIRST && pcache < p) {
    int it = 0;
    do {
      pcache = __hip_atomic_load(predf, __ATOMIC_ACQUIRE,
                                 __HIP_MEMORY_SCOPE_AGENT);
      if (pcache < p) __builtin_amdgcn_s_sleep(1);
    } while (pcache < p && ++it < (1 << 22));
  }
  // stage next phase's cost window (cols cb+32-lane .. cb+63-lane)
  W8 nxt = cur;
  if (dq >= 1 && dq <= 62)  nxt = load_w(crow, cb + 32 - lane);
  else if (dq != 65)        nxt = load_w_edge(crow, cb + 32 - lane);
  float bq = BIGF;
  if (!FIRST) {
    // dq=0: load post-acquire (r8 loaded it pre-acquire at init -> race)
    bq = (dq == 0) ? aload(&bp[lane]) : bqN;
    if (dq < 65) bqN = aload(&bp[min(cb + 32 + lane, MDIM - 1)]);
  }
  const bool edge = (dq < 2) || (dq > 63);
  if (edge) phase32<FIRST, true>(o, d, bq, cur, cb, lane, bw);
  else      phase32<FIRST, false>(o, d, bq, cur, cb, lane, bw);
  // release (lane 63 performed the bw stores; backend drains vmcnt here,
  // which also retires the nxt loads issued ~32 steps ago)
  if (lane == 63)
    __hip_atomic_store(myf, p + 1, __ATOMIC_RELEASE,
                       __HIP_MEMORY_SCOPE_AGENT);
  return nxt;
}

template <bool FIRST>
__device__ __forceinline__ void run_strip(
    int s, int lane, const float* __restrict__ crow,
    const float* __restrict__ bp, float* __restrict__ bw,
    int* myf, int* predf) {
  W8 cur = load_w_edge(crow, -lane);             // dq=0 window
  float o = BIGF;
  float d = (FIRST && lane == 0) ? 0.0f : BIGF;  // seeds R[0,0]=0 via diag
  float bqN = 0.0f;
  int pcache = 0;
  #pragma unroll 1
  for (int dq = 0; dq < 66; ++dq)
    cur = do_phase<FIRST>(dq, s, lane, cur, o, d, bqN, crow, bp, bw,
                          myf, predf, pcache);
  if (lane == 63)
    __hip_atomic_store(myf, 1 << 20, __ATOMIC_RELEASE,
                       __HIP_MEMORY_SCOPE_AGENT);
}

__global__ __launch_bounds__(64, 1) void softdtw_dp(
    const float* __restrict__ cost_base, float* __restrict__ bottom,
    int* __restrict__ flags) {
  const int bid = blockIdx.x;
  const int z = bid & 7;          // XCD grouping: matrix z -> XCD z
  if (z >= 3) return;
  const int s = bid >> 3;         // strip 0..31
  const int lane = threadIdx.x;

  const float* cost = cost_base + (size_t)z * MDIM * MDIM;
  const float* crow = cost + (size_t)(s * 64 + lane) * MDIM;
  float* bot_z = bottom + (size_t)z * NSTRIP * MDIM;
  const float* bp = bot_z + (size_t)(s > 0 ? s - 1 : 0) * MDIM;
  float* bw = bot_z + (size_t)s * MDIM;
  int* predf = &flags[z * NSTRIP + (s > 0 ? s - 1 : 0)];
  int* myf = &flags[z * NSTRIP + s];

  if (s == 0) run_strip<true>(s, lane, crow, bp, bw, myf, predf);
  else        run_strip<false>(s, lane, crow, bp, bw, myf, predf);
}

__global__ void dtw_init(int* __restrict__ flags) {
  if (threadIdx.x < 3 * NSTRIP) flags[threadIdx.x] = 0;
}

__global__ void combine(const float* __restrict__ bottom,
                        const float* __restrict__ gamma_p,
                        float* __restrict__ out) {
  float g = fmaxf(fabsf(gamma_p[0]), 1e-4f);
  float glog = 0.69314718056f * g;   // unscale: V = V' * g * ln2
  float b0 = bottom[0 * NSTRIP * MDIM + (NSTRIP - 1) * MDIM + 2047];
  float b1 = bottom[1 * NSTRIP * MDIM + (NSTRIP - 1) * MDIM + 2047];
  float b2 = bottom[2 * NSTRIP * MDIM + (NSTRIP - 1) * MDIM + 2047];
  out[0] = (b0 - 0.5f * (b1 + b2)) * glog;
}

extern "C" void kernel_launch(void* const* d_in, const int* in_sizes, int n_in,
                              void* d_out, int out_size, void* d_ws, size_t ws_size,
                              hipStream_t stream) {
  const float* x = (const float*)d_in[0];
  const float* y = (const float*)d_in[1];
  const float* gamma = (const float*)d_in[2];
  float* out = (float*)d_out;

  char* ws = (char*)d_ws;
  ushort* xb = (ushort*)ws;                                // 4 MB
  ushort* yb = (ushort*)(ws + (size_t)4 * 1024 * 1024);    // 4 MB
  float* cost = (float*)(ws + (size_t)8 * 1024 * 1024);    // 48 MB
  float* bottom = (float*)(ws + (size_t)56 * 1024 * 1024); // 768 KB
  int* flags = (int*)(ws + (size_t)59 * 1024 * 1024);      // 384 B

  normalize_rows<<<(2 * MDIM) / 4, 256, 0, stream>>>(x, y, xb, yb);

  dim3 ggrid(MDIM / 128, MDIM / 128, 3);
  gemm_cost_mfma<<<ggrid, 256, 0, stream>>>(xb, yb, cost, gamma);

  dtw_init<<<1, 128, 0, stream>>>(flags);

  softdtw_dp<<<256, 64, 0, stream>>>(cost, bottom, flags);

  combine<<<1, 1, 0, stream>>>(bottom, gamma, out);
}

// Round 10
// 1060.307 us; speedup vs baseline: 1.1521x; 1.1521x over previous
//
#include <hip/hip_runtime.h>
#include <hip/hip_bf16.h>
#include <math.h>

#define MDIM 2048
#define KDIM 1024
#define BIGF 1e9f
#define NSTRIP 32   // strips per matrix, 64 rows each (1 row per lane)
// KPH=32 steps/phase. Skew D=4 phases (128 steps). Strip s: phases [4s, 4s+65].

typedef unsigned short ushort;
typedef unsigned int uint;
typedef __attribute__((ext_vector_type(8))) short short8v;
typedef __attribute__((ext_vector_type(8))) ushort ushort8v;
typedef __attribute__((ext_vector_type(4))) float f32x4;
typedef __attribute__((ext_vector_type(4), aligned(4))) float f4u;

// ---------------- row normalization: one wave per row, emits bf16 ----------
__device__ __forceinline__ ushort f2bf(float f) {
  uint b = __builtin_bit_cast(uint, f);
  b += 0x7FFFu + ((b >> 16) & 1u);
  return (ushort)(b >> 16);
}

__global__ __launch_bounds__(256) void normalize_rows(
    const float* __restrict__ x, const float* __restrict__ y,
    ushort* __restrict__ xb, ushort* __restrict__ yb) {
  int wave = (blockIdx.x * blockDim.x + threadIdx.x) >> 6;
  int lane = threadIdx.x & 63;
  const float* src;
  ushort* dst;
  int row;
  if (wave < MDIM) { src = x; dst = xb; row = wave; }
  else             { src = y; dst = yb; row = wave - MDIM; }
  const float* r = src + (size_t)row * KDIM;
  ushort* w = dst + (size_t)row * KDIM;
  float ss = 0.f;
  for (int c = lane * 4; c < KDIM; c += 64 * 4) {
    float4 v = *(const float4*)&r[c];
    ss += v.x * v.x + v.y * v.y + v.z * v.z + v.w * v.w;
  }
  #pragma unroll
  for (int off = 32; off; off >>= 1) ss += __shfl_xor(ss, off, 64);
  float inv = 1.f / fmaxf(sqrtf(ss), 1e-12f);
  for (int c = lane * 4; c < KDIM; c += 64 * 4) {
    float4 v = *(const float4*)&r[c];
    uint2 o;
    o.x = (uint)f2bf(v.x * inv) | ((uint)f2bf(v.y * inv) << 16);
    o.y = (uint)f2bf(v.z * inv) | ((uint)f2bf(v.w * inv) << 16);
    *(uint2*)&w[c] = o;
  }
}

// ------------- cost GEMM (bf16 MFMA): C' = (1 - A.B^T) * kexp -------------
__global__ __launch_bounds__(256) void gemm_cost_mfma(
    const ushort* __restrict__ xb, const ushort* __restrict__ yb,
    float* __restrict__ cost_base, const float* __restrict__ gamma_p) {
  int z = blockIdx.z;
  const ushort* A = (z == 2) ? yb : xb;
  const ushort* B = (z == 0) ? yb : ((z == 1) ? xb : yb);
  float* C = cost_base + (size_t)z * MDIM * MDIM;
  float g = fmaxf(fabsf(gamma_p[0]), 1e-4f);
  float kexp = 1.44269504089f / g;

  __shared__ ushort As[128 * 64];
  __shared__ ushort Bs[128 * 64];

  int tid = threadIdx.x;
  int w = tid >> 6, l = tid & 63;
  int wr = w >> 1, wc = w & 1;
  int abase = blockIdx.y * 128;
  int bbase = blockIdx.x * 128;

  f32x4 acc[4][4] = {};

  for (int k0 = 0; k0 < KDIM; k0 += 64) {
    ushort8v va[4], vb[4];
    #pragma unroll
    for (int q = 0; q < 4; ++q) {
      int slot = q * 256 + tid;
      int row = slot >> 3, sc = slot & 7;
      va[q] = *(const ushort8v*)&A[(size_t)(abase + row) * KDIM + k0 + sc * 8];
      vb[q] = *(const ushort8v*)&B[(size_t)(bbase + row) * KDIM + k0 + sc * 8];
    }
    __syncthreads();
    #pragma unroll
    for (int q = 0; q < 4; ++q) {
      int slot = q * 256 + tid;
      int row = slot >> 3, sc = slot & 7;
      int off = row * 64 + ((sc ^ (row & 7)) << 3);
      *(ushort8v*)&As[off] = va[q];
      *(ushort8v*)&Bs[off] = vb[q];
    }
    __syncthreads();
    #pragma unroll
    for (int kk = 0; kk < 2; ++kk) {
      short8v af[4], bf[4];
      #pragma unroll
      for (int m = 0; m < 4; ++m) {
        int row = wr * 64 + m * 16 + (l & 15);
        int kg = kk * 4 + (l >> 4);
        af[m] = *(const short8v*)&As[row * 64 + ((kg ^ (row & 7)) << 3)];
      }
      #pragma unroll
      for (int n = 0; n < 4; ++n) {
        int row = wc * 64 + n * 16 + (l & 15);
        int kg = kk * 4 + (l >> 4);
        bf[n] = *(const short8v*)&Bs[row * 64 + ((kg ^ (row & 7)) << 3)];
      }
      #pragma unroll
      for (int m = 0; m < 4; ++m)
        #pragma unroll
        for (int n = 0; n < 4; ++n)
          acc[m][n] = __builtin_amdgcn_mfma_f32_16x16x32_bf16(
              af[m], bf[n], acc[m][n], 0, 0, 0);
    }
  }
  #pragma unroll
  for (int m = 0; m < 4; ++m) {
    int row0 = abase + wr * 64 + m * 16 + (l >> 4) * 4;
    #pragma unroll
    for (int n = 0; n < 4; ++n) {
      int col = bbase + wc * 64 + n * 16 + (l & 15);
      f32x4 v = acc[m][n];
      #pragma unroll
      for (int r = 0; r < 4; ++r)
        C[(size_t)(row0 + r) * MDIM + col] = (1.0f - v[r]) * kexp;
    }
  }
}

// ---------------- soft-DTW: asm-pinned register wavefront, KPH=32 ----------
__device__ __forceinline__ float fexp2(float x) { return __builtin_amdgcn_exp2f(x); }
__device__ __forceinline__ float flog2(float x) { return __builtin_amdgcn_logf(x); }

__device__ __forceinline__ float shr1(float v) {  // lane i <- lane i-1
  int r = __builtin_amdgcn_update_dpp(__builtin_bit_cast(int, v),
                                      __builtin_bit_cast(int, v),
                                      0x138 /*wave_shr:1*/, 0xF, 0xF, false);
  return __builtin_bit_cast(float, r);
}

// staged cost window: 8 named f4u SSA values (asm outputs -> no alloca)
struct W8 { f4u v0, v1, v2, v3, v4, v5, v6, v7; };

// asm volatile loads: compiler cannot sink/reorder/delete the issue point.
// Drain contract: the lane-63 agent-release at each phase end emits
// s_waitcnt vmcnt(0), so loads issued at phase-top p are complete before
// any phase-(p+1) consumer. Loop-carried register copies happen at the
// backedge, i.e. after that drain -> in-flight-output hazard closed.
__device__ __forceinline__ float gload1(const float* p) {
  float r;
  asm volatile("global_load_dword %0, %1, off" : "=v"(r) : "v"(p));
  return r;
}

__device__ __forceinline__ W8 load_w_asm(const float* __restrict__ crow,
                                         int base) {
  W8 w;
  const float* b = crow + base;
  asm volatile("global_load_dwordx4 %0, %1, off"            : "=v"(w.v0) : "v"(b));
  asm volatile("global_load_dwordx4 %0, %1, off offset:16"  : "=v"(w.v1) : "v"(b));
  asm volatile("global_load_dwordx4 %0, %1, off offset:32"  : "=v"(w.v2) : "v"(b));
  asm volatile("global_load_dwordx4 %0, %1, off offset:48"  : "=v"(w.v3) : "v"(b));
  asm volatile("global_load_dwordx4 %0, %1, off offset:64"  : "=v"(w.v4) : "v"(b));
  asm volatile("global_load_dwordx4 %0, %1, off offset:80"  : "=v"(w.v5) : "v"(b));
  asm volatile("global_load_dwordx4 %0, %1, off offset:96"  : "=v"(w.v6) : "v"(b));
  asm volatile("global_load_dwordx4 %0, %1, off offset:112" : "=v"(w.v7) : "v"(b));
  return w;
}

__device__ __forceinline__ f4u eload4(const float* __restrict__ crow, int base) {
  float a = gload1(crow + min(max(base + 0, 0), MDIM - 1));
  float b = gload1(crow + min(max(base + 1, 0), MDIM - 1));
  float c = gload1(crow + min(max(base + 2, 0), MDIM - 1));
  float d = gload1(crow + min(max(base + 3, 0), MDIM - 1));
  return (f4u){a, b, c, d};
}

__device__ __forceinline__ W8 load_w_edge_asm(const float* __restrict__ crow,
                                              int base) {
  W8 w;
  w.v0 = eload4(crow, base +  0);
  w.v1 = eload4(crow, base +  4);
  w.v2 = eload4(crow, base +  8);
  w.v3 = eload4(crow, base + 12);
  w.v4 = eload4(crow, base + 16);
  w.v5 = eload4(crow, base + 20);
  w.v6 = eload4(crow, base + 24);
  w.v7 = eload4(crow, base + 28);
  return w;
}

// zero-instruction pin: forces window+bq into VGPRs here and creates data
// deps so body VALU ops cannot hoist above the preceding release drain.
__device__ __forceinline__ void pinw(W8& w, float& b) {
  asm volatile("" : "+v"(w.v0), "+v"(w.v1), "+v"(w.v2), "+v"(w.v3),
                    "+v"(w.v4), "+v"(w.v5), "+v"(w.v6), "+v"(w.v7), "+v"(b));
}

// one 32-step phase body; lane l owns row (64s + l); col at step u: cb+u-l.
template <bool FIRST, bool EDGE>
__device__ __forceinline__ void phase32(
    float& o, float& d, float bq, W8 w, int cb, int lane,
    float* __restrict__ bw) {
  const bool l0 = (lane == 0);
  const bool l63 = (lane == 63);
  float h0, h1, h2, h3;
  #pragma unroll
  for (int u = 0; u < 32; ++u) {
    f4u q = (u < 4) ? w.v0 : (u < 8) ? w.v1 : (u < 12) ? w.v2
          : (u < 16) ? w.v3 : (u < 20) ? w.v4 : (u < 24) ? w.v5
          : (u < 28) ? w.v6 : w.v7;
    float cv = q[u & 3];
    float t = shr1(o);
    float av;
    if (FIRST) {
      av = l0 ? BIGF : t;
    } else {
      float rv = __builtin_bit_cast(
          float, __builtin_amdgcn_readlane(__builtin_bit_cast(int, bq), u));
      av = l0 ? rv : t;
    }
    float mn, md, mx;
    asm("v_min3_f32 %0, %1, %2, %3" : "=v"(mn) : "v"(d), "v"(av), "v"(o));
    asm("v_med3_f32 %0, %1, %2, %3" : "=v"(md) : "v"(d), "v"(av), "v"(o));
    asm("v_max3_f32 %0, %1, %2, %3" : "=v"(mx) : "v"(d), "v"(av), "v"(o));
    float e = 1.0f + fexp2(mn - md) + fexp2(mn - mx);
    float n = cv + (mn - flog2(e));
    if (EDGE) {
      int c = cb + u - lane;
      bool valid = ((unsigned)c < (unsigned)MDIM);
      n = valid ? n : BIGF;
      if (l63 && valid) bw[c] = n;
    } else {
      if ((u & 3) == 0) h0 = n;
      else if ((u & 3) == 1) h1 = n;
      else if ((u & 3) == 2) h2 = n;
      else {
        h3 = n;
        if (l63) *(f4u*)&bw[cb + u - 66] = (f4u){h0, h1, h2, h3};
      }
    }
    d = av;
    o = n;
  }
}

// one full phase: acquire -> asm-stage next window -> pin -> body -> release.
template <bool FIRST>
__device__ __forceinline__ W8 do_phase(
    int dq, int s, int lane, W8 cur, float& o, float& d, float& bqN,
    const float* __restrict__ crow, const float* __restrict__ bp,
    float* __restrict__ bw, int* myf, int* predf, int& pcache) {
  const int p = 4 * s + dq;
  const int cb = dq << 5;
  if (!FIRST && pcache < p) {
    int it = 0;
    do {
      pcache = __hip_atomic_load(predf, __ATOMIC_ACQUIRE,
                                 __HIP_MEMORY_SCOPE_AGENT);
      if (pcache < p) __builtin_amdgcn_s_sleep(1);
    } while (pcache < p && ++it < (1 << 22));
  }
  // stage next phase's cost window (cols cb+32-lane .. cb+63-lane)
  W8 nxt = cur;
  if (dq >= 1 && dq <= 62)  nxt = load_w_asm(crow, cb + 32 - lane);
  else if (dq != 65)        nxt = load_w_edge_asm(crow, cb + 32 - lane);
  float bq = BIGF;
  if (!FIRST) {
    if (dq == 0) {
      bq = gload1(&bp[lane]);    // post-acquire (r8 pre-acquire race fixed)
      asm volatile("s_waitcnt vmcnt(0)" ::: "memory");
      __builtin_amdgcn_sched_barrier(0);
    } else {
      bq = bqN;                  // loaded last phase, drained by release
    }
    if (dq < 65) bqN = gload1(&bp[min(cb + 32 + lane, MDIM - 1)]);
  }
  pinw(cur, bq);
  __builtin_amdgcn_sched_barrier(0);
  const bool edge = (dq < 2) || (dq > 63);
  if (edge) phase32<FIRST, true>(o, d, bq, cur, cb, lane, bw);
  else      phase32<FIRST, false>(o, d, bq, cur, cb, lane, bw);
  // lane-63 agent release: backend drains vmcnt(0) first -> retires this
  // phase's bw stores AND the nxt/bqN loads issued ~2000 cy ago.
  if (lane == 63)
    __hip_atomic_store(myf, p + 1, __ATOMIC_RELEASE,
                       __HIP_MEMORY_SCOPE_AGENT);
  return nxt;
}

template <bool FIRST>
__device__ __forceinline__ void run_strip(
    int s, int lane, const float* __restrict__ crow,
    const float* __restrict__ bp, float* __restrict__ bw,
    int* myf, int* predf) {
  W8 cur = load_w_edge_asm(crow, -lane);         // dq=0 window
  asm volatile("s_waitcnt vmcnt(0)" ::: "memory");
  __builtin_amdgcn_sched_barrier(0);
  float o = BIGF;
  float d = (FIRST && lane == 0) ? 0.0f : BIGF;  // seeds R[0,0]=0 via diag
  float bqN = 0.0f;
  int pcache = 0;
  #pragma unroll 1
  for (int dq = 0; dq < 66; ++dq)
    cur = do_phase<FIRST>(dq, s, lane, cur, o, d, bqN, crow, bp, bw,
                          myf, predf, pcache);
  if (lane == 63)
    __hip_atomic_store(myf, 1 << 20, __ATOMIC_RELEASE,
                       __HIP_MEMORY_SCOPE_AGENT);
}

__global__ __launch_bounds__(64, 1) void softdtw_dp(
    const float* __restrict__ cost_base, float* __restrict__ bottom,
    int* __restrict__ flags) {
  const int bid = blockIdx.x;
  const int z = bid & 7;          // XCD grouping: matrix z -> XCD z
  if (z >= 3) return;
  const int s = bid >> 3;         // strip 0..31
  const int lane = threadIdx.x;

  const float* cost = cost_base + (size_t)z * MDIM * MDIM;
  const float* crow = cost + (size_t)(s * 64 + lane) * MDIM;
  float* bot_z = bottom + (size_t)z * NSTRIP * MDIM;
  const float* bp = bot_z + (size_t)(s > 0 ? s - 1 : 0) * MDIM;
  float* bw = bot_z + (size_t)s * MDIM;
  int* predf = &flags[z * NSTRIP + (s > 0 ? s - 1 : 0)];
  int* myf = &flags[z * NSTRIP + s];

  if (s == 0) run_strip<true>(s, lane, crow, bp, bw, myf, predf);
  else        run_strip<false>(s, lane, crow, bp, bw, myf, predf);
}

__global__ void dtw_init(int* __restrict__ flags) {
  if (threadIdx.x < 3 * NSTRIP) flags[threadIdx.x] = 0;
}

__global__ void combine(const float* __restrict__ bottom,
                        const float* __restrict__ gamma_p,
                        float* __restrict__ out) {
  float g = fmaxf(fabsf(gamma_p[0]), 1e-4f);
  float glog = 0.69314718056f * g;   // unscale: V = V' * g * ln2
  float b0 = bottom[0 * NSTRIP * MDIM + (NSTRIP - 1) * MDIM + 2047];
  float b1 = bottom[1 * NSTRIP * MDIM + (NSTRIP - 1) * MDIM + 2047];
  float b2 = bottom[2 * NSTRIP * MDIM + (NSTRIP - 1) * MDIM + 2047];
  out[0] = (b0 - 0.5f * (b1 + b2)) * glog;
}

extern "C" void kernel_launch(void* const* d_in, const int* in_sizes, int n_in,
                              void* d_out, int out_size, void* d_ws, size_t ws_size,
                              hipStream_t stream) {
  const float* x = (const float*)d_in[0];
  const float* y = (const float*)d_in[1];
  const float* gamma = (const float*)d_in[2];
  float* out = (float*)d_out;

  char* ws = (char*)d_ws;
  ushort* xb = (ushort*)ws;                                // 4 MB
  ushort* yb = (ushort*)(ws + (size_t)4 * 1024 * 1024);    // 4 MB
  float* cost = (float*)(ws + (size_t)8 * 1024 * 1024);    // 48 MB
  float* bottom = (float*)(ws + (size_t)56 * 1024 * 1024); // 768 KB
  int* flags = (int*)(ws + (size_t)59 * 1024 * 1024);      // 384 B

  normalize_rows<<<(2 * MDIM) / 4, 256, 0, stream>>>(x, y, xb, yb);

  dim3 ggrid(MDIM / 128, MDIM / 128, 3);
  gemm_cost_mfma<<<ggrid, 256, 0, stream>>>(xb, yb, cost, gamma);

  dtw_init<<<1, 128, 0, stream>>>(flags);

  softdtw_dp<<<256, 64, 0, stream>>>(cost, bottom, flags);

  combine<<<1, 1, 0, stream>>>(bottom, gamma, out);
}

// Round 12
// 1009.599 us; speedup vs baseline: 1.2100x; 1.0502x over previous
//
#include <hip/hip_runtime.h>
#include <hip/hip_bf16.h>
#include <math.h>

#define MDIM 2048
#define KDIM 1024
#define BIGF 1e9f
#define NSTRIP 32   // strips per matrix, 64 rows each (1 row per lane)
// KPH=64 steps/phase. Skew D=2 phases (128 steps). Strip s: phases [2s, 2s+32].

typedef unsigned short ushort;
typedef unsigned int uint;
typedef __attribute__((ext_vector_type(8))) short short8v;
typedef __attribute__((ext_vector_type(8))) ushort ushort8v;
typedef __attribute__((ext_vector_type(4))) float f32x4;
typedef __attribute__((ext_vector_type(4), aligned(4))) float f4u;

// ---------------- row normalization: one wave per row, emits bf16 ----------
__device__ __forceinline__ ushort f2bf(float f) {
  uint b = __builtin_bit_cast(uint, f);
  b += 0x7FFFu + ((b >> 16) & 1u);
  return (ushort)(b >> 16);
}

__global__ __launch_bounds__(256) void normalize_rows(
    const float* __restrict__ x, const float* __restrict__ y,
    ushort* __restrict__ xb, ushort* __restrict__ yb) {
  int wave = (blockIdx.x * blockDim.x + threadIdx.x) >> 6;
  int lane = threadIdx.x & 63;
  const float* src;
  ushort* dst;
  int row;
  if (wave < MDIM) { src = x; dst = xb; row = wave; }
  else             { src = y; dst = yb; row = wave - MDIM; }
  const float* r = src + (size_t)row * KDIM;
  ushort* w = dst + (size_t)row * KDIM;
  float ss = 0.f;
  for (int c = lane * 4; c < KDIM; c += 64 * 4) {
    float4 v = *(const float4*)&r[c];
    ss += v.x * v.x + v.y * v.y + v.z * v.z + v.w * v.w;
  }
  #pragma unroll
  for (int off = 32; off; off >>= 1) ss += __shfl_xor(ss, off, 64);
  float inv = 1.f / fmaxf(sqrtf(ss), 1e-12f);
  for (int c = lane * 4; c < KDIM; c += 64 * 4) {
    float4 v = *(const float4*)&r[c];
    uint2 o;
    o.x = (uint)f2bf(v.x * inv) | ((uint)f2bf(v.y * inv) << 16);
    o.y = (uint)f2bf(v.z * inv) | ((uint)f2bf(v.w * inv) << 16);
    *(uint2*)&w[c] = o;
  }
}

// ------------- cost GEMM (bf16 MFMA): C' = (1 - A.B^T) * kexp -------------
__global__ __launch_bounds__(256) void gemm_cost_mfma(
    const ushort* __restrict__ xb, const ushort* __restrict__ yb,
    float* __restrict__ cost_base, const float* __restrict__ gamma_p) {
  int z = blockIdx.z;
  const ushort* A = (z == 2) ? yb : xb;
  const ushort* B = (z == 0) ? yb : ((z == 1) ? xb : yb);
  float* C = cost_base + (size_t)z * MDIM * MDIM;
  float g = fmaxf(fabsf(gamma_p[0]), 1e-4f);
  float kexp = 1.44269504089f / g;

  __shared__ ushort As[128 * 64];
  __shared__ ushort Bs[128 * 64];

  int tid = threadIdx.x;
  int w = tid >> 6, l = tid & 63;
  int wr = w >> 1, wc = w & 1;
  int abase = blockIdx.y * 128;
  int bbase = blockIdx.x * 128;

  f32x4 acc[4][4] = {};

  for (int k0 = 0; k0 < KDIM; k0 += 64) {
    ushort8v va[4], vb[4];
    #pragma unroll
    for (int q = 0; q < 4; ++q) {
      int slot = q * 256 + tid;
      int row = slot >> 3, sc = slot & 7;
      va[q] = *(const ushort8v*)&A[(size_t)(abase + row) * KDIM + k0 + sc * 8];
      vb[q] = *(const ushort8v*)&B[(size_t)(bbase + row) * KDIM + k0 + sc * 8];
    }
    __syncthreads();
    #pragma unroll
    for (int q = 0; q < 4; ++q) {
      int slot = q * 256 + tid;
      int row = slot >> 3, sc = slot & 7;
      int off = row * 64 + ((sc ^ (row & 7)) << 3);
      *(ushort8v*)&As[off] = va[q];
      *(ushort8v*)&Bs[off] = vb[q];
    }
    __syncthreads();
    #pragma unroll
    for (int kk = 0; kk < 2; ++kk) {
      short8v af[4], bf[4];
      #pragma unroll
      for (int m = 0; m < 4; ++m) {
        int row = wr * 64 + m * 16 + (l & 15);
        int kg = kk * 4 + (l >> 4);
        af[m] = *(const short8v*)&As[row * 64 + ((kg ^ (row & 7)) << 3)];
      }
      #pragma unroll
      for (int n = 0; n < 4; ++n) {
        int row = wc * 64 + n * 16 + (l & 15);
        int kg = kk * 4 + (l >> 4);
        bf[n] = *(const short8v*)&Bs[row * 64 + ((kg ^ (row & 7)) << 3)];
      }
      #pragma unroll
      for (int m = 0; m < 4; ++m)
        #pragma unroll
        for (int n = 0; n < 4; ++n)
          acc[m][n] = __builtin_amdgcn_mfma_f32_16x16x32_bf16(
              af[m], bf[n], acc[m][n], 0, 0, 0);
    }
  }
  #pragma unroll
  for (int m = 0; m < 4; ++m) {
    int row0 = abase + wr * 64 + m * 16 + (l >> 4) * 4;
    #pragma unroll
    for (int n = 0; n < 4; ++n) {
      int col = bbase + wc * 64 + n * 16 + (l & 15);
      f32x4 v = acc[m][n];
      #pragma unroll
      for (int r = 0; r < 4; ++r)
        C[(size_t)(row0 + r) * MDIM + col] = (1.0f - v[r]) * kexp;
    }
  }
}

// ------ soft-DTW: diagonal-major LDS ring staged via global_load_lds -------
__device__ __forceinline__ float fexp2(float x) { return __builtin_amdgcn_exp2f(x); }
__device__ __forceinline__ float flog2(float x) { return __builtin_amdgcn_logf(x); }

__device__ __forceinline__ float shr1(float v) {  // lane i <- lane i-1
  int r = __builtin_amdgcn_update_dpp(__builtin_bit_cast(int, v),
                                      __builtin_bit_cast(int, v),
                                      0x138 /*wave_shr:1*/, 0xF, 0xF, false);
  return __builtin_bit_cast(float, r);
}

__device__ __forceinline__ float aload(const float* p) {
  return __hip_atomic_load(p, __ATOMIC_RELAXED, __HIP_MEMORY_SCOPE_AGENT);
}

// HW gather of one anti-diagonal: per-lane global addr, LDS dest = uniform
// base + lane*4 (global_load_lds semantics) -> diag-major slot, 0 VGPRs.
__device__ __forceinline__ void gather_diag(const float* gaddr, float* laddr) {
  __builtin_amdgcn_global_load_lds(
      (const __attribute__((address_space(1))) void*)gaddr,
      (__attribute__((address_space(3))) void*)laddr, 4, 0, 0);
}

// one 8-step group: consume bank c0..c7 (diag t=cb+u0..), prefetch next
// group's ds_reads into n0..n7. Bank regs are scalars -> ~16 VGPRs total.
template <bool FIRST, bool EDGE>
__device__ __forceinline__ void group8(
    int dq, int g, int u0, int lane, float& o, float& d, float bq,
    float& c0, float& c1, float& c2, float& c3,
    float& c4, float& c5, float& c6, float& c7,
    float& n0, float& n1, float& n2, float& n3,
    float& n4, float& n5, float& n6, float& n7,
    const float* __restrict__ ring, float* __restrict__ bw,
    float& h0, float& h1, float& h2, float& h3) {
  const int cb = dq << 6;
  if (g < 7) {  // issue next group's LDS reads (bank = lane%32, conflict-free)
    const int b = ((dq & 1) << 12) + ((g + 1) << 9) + lane;
    n0 = ring[b];       n1 = ring[b + 64];
    n2 = ring[b + 128]; n3 = ring[b + 192];
    n4 = ring[b + 256]; n5 = ring[b + 320];
    n6 = ring[b + 384]; n7 = ring[b + 448];
  }
  const bool l0 = (lane == 0), l63 = (lane == 63);
  #pragma unroll
  for (int j = 0; j < 8; ++j) {
    const int u = u0 + j;
    float cv = (j == 0) ? c0 : (j == 1) ? c1 : (j == 2) ? c2 : (j == 3) ? c3
             : (j == 4) ? c4 : (j == 5) ? c5 : (j == 6) ? c6 : c7;
    float t = shr1(o);
    float av;
    if (FIRST) {
      av = l0 ? BIGF : t;
    } else {
      float rv = __builtin_bit_cast(
          float, __builtin_amdgcn_readlane(__builtin_bit_cast(int, bq), u));
      av = l0 ? rv : t;
    }
    float mn, md, mx;
    asm("v_min3_f32 %0, %1, %2, %3" : "=v"(mn) : "v"(d), "v"(av), "v"(o));
    asm("v_med3_f32 %0, %1, %2, %3" : "=v"(md) : "v"(d), "v"(av), "v"(o));
    asm("v_max3_f32 %0, %1, %2, %3" : "=v"(mx) : "v"(d), "v"(av), "v"(o));
    float e = 1.0f + fexp2(mn - md) + fexp2(mn - mx);
    float n = cv + (mn - flog2(e));
    if (EDGE) {
      int c = cb + u - lane;
      bool valid = ((unsigned)c < (unsigned)MDIM);
      n = valid ? n : BIGF;
      if (l63 && valid) bw[c] = n;
    } else {
      if ((u & 3) == 0) h0 = n;
      else if ((u & 3) == 1) h1 = n;
      else if ((u & 3) == 2) h2 = n;
      else {
        h3 = n;
        if (l63) *(f4u*)&bw[cb + u - 66] = (f4u){h0, h1, h2, h3};
      }
    }
    d = av;
    o = n;
  }
}

template <bool FIRST, bool EDGE>
__device__ __forceinline__ void phase64(
    int dq, int lane, float& o, float& d, float bq,
    const float* __restrict__ crow, float* __restrict__ ring,
    float* __restrict__ bw) {
  // drain pending ds_reads of the half we are about to overwrite (staging)
  asm volatile("s_waitcnt lgkmcnt(0)" ::: "memory");
  __builtin_amdgcn_sched_barrier(0);
  // group-0 reads (slots staged last phase; retired by phase-top vmcnt(0))
  const int rb = ((dq & 1) << 12) + lane;
  float a0 = ring[rb],       a1 = ring[rb + 64];
  float a2 = ring[rb + 128], a3 = ring[rb + 192];
  float a4 = ring[rb + 256], a5 = ring[rb + 320];
  float a6 = ring[rb + 384], a7 = ring[rb + 448];
  // stage next window [cb+64, cb+127] into the other ring half (async HW path)
  if (dq < 32) {
    const int cb = dq << 6;
    float* lhalf = ring + ((((dq & 1) ^ 1)) << 12);
    #pragma unroll 8
    for (int k = 0; k < 64; ++k) {
      int col = min(max(cb + 64 + k - lane, 0), MDIM - 1);
      gather_diag(crow + col, lhalf + (k << 6));
    }
  }
  float b0 = 0, b1 = 0, b2 = 0, b3 = 0, b4 = 0, b5 = 0, b6 = 0, b7 = 0;
  float h0 = 0, h1 = 0, h2 = 0, h3 = 0;
  group8<FIRST, EDGE>(dq, 0,  0, lane, o, d, bq, a0,a1,a2,a3,a4,a5,a6,a7,
                      b0,b1,b2,b3,b4,b5,b6,b7, ring, bw, h0,h1,h2,h3);
  group8<FIRST, EDGE>(dq, 1,  8, lane, o, d, bq, b0,b1,b2,b3,b4,b5,b6,b7,
                      a0,a1,a2,a3,a4,a5,a6,a7, ring, bw, h0,h1,h2,h3);
  group8<FIRST, EDGE>(dq, 2, 16, lane, o, d, bq, a0,a1,a2,a3,a4,a5,a6,a7,
                      b0,b1,b2,b3,b4,b5,b6,b7, ring, bw, h0,h1,h2,h3);
  group8<FIRST, EDGE>(dq, 3, 24, lane, o, d, bq, b0,b1,b2,b3,b4,b5,b6,b7,
                      a0,a1,a2,a3,a4,a5,a6,a7, ring, bw, h0,h1,h2,h3);
  group8<FIRST, EDGE>(dq, 4, 32, lane, o, d, bq, a0,a1,a2,a3,a4,a5,a6,a7,
                      b0,b1,b2,b3,b4,b5,b6,b7, ring, bw, h0,h1,h2,h3);
  group8<FIRST, EDGE>(dq, 5, 40, lane, o, d, bq, b0,b1,b2,b3,b4,b5,b6,b7,
                      a0,a1,a2,a3,a4,a5,a6,a7, ring, bw, h0,h1,h2,h3);
  group8<FIRST, EDGE>(dq, 6, 48, lane, o, d, bq, a0,a1,a2,a3,a4,a5,a6,a7,
                      b0,b1,b2,b3,b4,b5,b6,b7, ring, bw, h0,h1,h2,h3);
  group8<FIRST, EDGE>(dq, 7, 56, lane, o, d, bq, b0,b1,b2,b3,b4,b5,b6,b7,
                      a0,a1,a2,a3,a4,a5,a6,a7, ring, bw, h0,h1,h2,h3);
}

template <bool FIRST>
__device__ __forceinline__ void run_strip(
    int s, int lane, const float* __restrict__ crow,
    const float* __restrict__ bp, float* __restrict__ bw,
    int* myf, int* predf, float* __restrict__ ring) {
  // prestage diagonals t=0..63 into ring slots 0..63 (parity of dq=0)
  #pragma unroll 8
  for (int t = 0; t < 64; ++t) {
    int col = min(max(t - lane, 0), MDIM - 1);
    gather_diag(crow + col, ring + (t << 6));
  }
  float o = BIGF;
  float d = (FIRST && lane == 0) ? 0.0f : BIGF;  // seeds R[0,0]=0 via diag
  float bq = BIGF, bqN = BIGF;
  int pcache = 0;
  #pragma unroll 1
  for (int dq = 0; dq <= 32; ++dq) {
    const int p = 2 * s + dq;
    const int cb = dq << 6;
    if (!FIRST && pcache < p) {
      int it = 0;
      do {
        pcache = __hip_atomic_load(predf, __ATOMIC_ACQUIRE,
                                   __HIP_MEMORY_SCOPE_AGENT);
        if (pcache < p) __builtin_amdgcn_s_sleep(1);
      } while (pcache < p && ++it < (1 << 22));
    }
    if (!FIRST) bq = (dq == 0) ? aload(&bp[lane]) : bqN;
    // retire last phase's staging gathers (+ dq0 bq / prestage) before reads
    asm volatile("s_waitcnt vmcnt(0)" ::: "memory");
    __builtin_amdgcn_sched_barrier(0);
    const bool edge = (dq == 0) || (dq == 32);
    if (edge) phase64<FIRST, true >(dq, lane, o, d, bq, crow, ring, bw);
    else      phase64<FIRST, false>(dq, lane, o, d, bq, crow, ring, bw);
    // next phase's bottom chunk: issued now, retired by next phase-top vmcnt
    if (!FIRST && dq < 32)
      bqN = aload(&bp[min(cb + 64 + lane, MDIM - 1)]);
    if (lane == 63)
      __hip_atomic_store(myf, p + 1, __ATOMIC_RELEASE,
                         __HIP_MEMORY_SCOPE_AGENT);
  }
  if (lane == 63)
    __hip_atomic_store(myf, 1 << 20, __ATOMIC_RELEASE,
                       __HIP_MEMORY_SCOPE_AGENT);
}

__global__ __launch_bounds__(64) void softdtw_dp(
    const float* __restrict__ cost_base, float* __restrict__ bottom,
    int* __restrict__ flags) {
  __shared__ float ring[128 * 64];  // 32 KB diag-major double window
  const int bid = blockIdx.x;
  const int z = bid & 7;            // XCD grouping: matrix z -> XCD z
  if (z >= 3) return;
  const int s = bid >> 3;           // strip 0..31
  const int lane = threadIdx.x;

  const float* cost = cost_base + (size_t)z * MDIM * MDIM;
  const float* crow = cost + (size_t)(s * 64 + lane) * MDIM;
  float* bot_z = bottom + (size_t)z * NSTRIP * MDIM;
  const float* bp = bot_z + (size_t)(s > 0 ? s - 1 : 0) * MDIM;
  float* bw = bot_z + (size_t)s * MDIM;
  int* predf = &flags[z * NSTRIP + (s > 0 ? s - 1 : 0)];
  int* myf = &flags[z * NSTRIP + s];

  if (s == 0) run_strip<true >(s, lane, crow, bp, bw, myf, predf, ring);
  else        run_strip<false>(s, lane, crow, bp, bw, myf, predf, ring);
}

__global__ void dtw_init(int* __restrict__ flags) {
  if (threadIdx.x < 3 * NSTRIP) flags[threadIdx.x] = 0;
}

__global__ void combine(const float* __restrict__ bottom,
                        const float* __restrict__ gamma_p,
                        float* __restrict__ out) {
  float g = fmaxf(fabsf(gamma_p[0]), 1e-4f);
  float glog = 0.69314718056f * g;   // unscale: V = V' * g * ln2
  float b0 = bottom[0 * NSTRIP * MDIM + (NSTRIP - 1) * MDIM + 2047];
  float b1 = bottom[1 * NSTRIP * MDIM + (NSTRIP - 1) * MDIM + 2047];
  float b2 = bottom[2 * NSTRIP * MDIM + (NSTRIP - 1) * MDIM + 2047];
  out[0] = (b0 - 0.5f * (b1 + b2)) * glog;
}

extern "C" void kernel_launch(void* const* d_in, const int* in_sizes, int n_in,
                              void* d_out, int out_size, void* d_ws, size_t ws_size,
                              hipStream_t stream) {
  const float* x = (const float*)d_in[0];
  const float* y = (const float*)d_in[1];
  const float* gamma = (const float*)d_in[2];
  float* out = (float*)d_out;

  char* ws = (char*)d_ws;
  ushort* xb = (ushort*)ws;                                // 4 MB
  ushort* yb = (ushort*)(ws + (size_t)4 * 1024 * 1024);    // 4 MB
  float* cost = (float*)(ws + (size_t)8 * 1024 * 1024);    // 48 MB
  float* bottom = (float*)(ws + (size_t)56 * 1024 * 1024); // 768 KB
  int* flags = (int*)(ws + (size_t)59 * 1024 * 1024);      // 384 B

  normalize_rows<<<(2 * MDIM) / 4, 256, 0, stream>>>(x, y, xb, yb);

  dim3 ggrid(MDIM / 128, MDIM / 128, 3);
  gemm_cost_mfma<<<ggrid, 256, 0, stream>>>(xb, yb, cost, gamma);

  dtw_init<<<1, 128, 0, stream>>>(flags);

  softdtw_dp<<<256, 64, 0, stream>>>(cost, bottom, flags);

  combine<<<1, 1, 0, stream>>>(bottom, gamma, out);
}